// Round 8
// baseline (573.858 us; speedup 1.0000x reference)
//
#include <hip/hip_runtime.h>
#include <math.h>

#define D_DIM   256
#define N_ROWS  16384
#define K_CODES 8192
#define BM      128
#define BN      128
#define KCHUNK  1024
#define NCHUNK  (K_CODES / KCHUNK)   // 8

typedef __attribute__((ext_vector_type(8))) short s8v;           // 8 bf16 (A/B frag)
typedef __attribute__((ext_vector_type(4))) float f4v;           // 4 f32  (C/D frag)
typedef __attribute__((ext_vector_type(4))) unsigned short us4;  // 4 bf16 (8B write)
typedef unsigned long long u64;
typedef unsigned int u32;

// out layout: [0, 4194304) z_q_st | [4194304, 4210688) indices (as float) | [4210688] vq_loss
#define IDX_OFF  ((size_t)N_ROWS * D_DIM)
#define LOSS_OFF (IDX_OFF + N_ROWS)

// ws layout:
//   [0, 2MB)        u64 cand[N_ROWS][NCHUNK][2]
//   [2MB, +32KB)    float enorm[8192]
//   [2MB+32KB,+16K) float partials[4096]
//   [4MB, 12MB)     bf16 zh[16384][256]  (XOR-permuted per 128B block: gl2lds source)
//   [12MB, 20MB)    bf16 zl[16384][256]  (linear: per-lane register loads)
//   [20MB, 24MB)    bf16 eh[8192][256]   (linear: per-lane register loads)
//   [24MB, 28MB)    bf16 el[8192][256]   (linear)
#define WS_ENORM_OFF    (2u * 1024u * 1024u)
#define WS_PARTIAL_OFF  (WS_ENORM_OFF + 32768u)
#define WS_ZH_OFF       (4u * 1024u * 1024u)
#define WS_ZL_OFF       (12u * 1024u * 1024u)
#define WS_EH_OFF       (20u * 1024u * 1024u)
#define WS_EL_OFF       (24u * 1024u * 1024u)
#define WS_NEED         (28u * 1024u * 1024u)

__device__ __forceinline__ unsigned short f2bf(float f) {   // fp32 -> bf16 RNE
    u32 u = __float_as_uint(f);
    return (unsigned short)((u + 0x7fffu + ((u >> 16) & 1u)) >> 16);
}
__device__ __forceinline__ float bf2f(unsigned short b) {
    return __uint_as_float(((u32)b) << 16);
}
__device__ __forceinline__ u32 f2ord(float f) {             // monotonic fp32 -> u32
    u32 u = __float_as_uint(f);
    return (u & 0x80000000u) ? ~u : (u | 0x80000000u);
}
__device__ __forceinline__ void gl2lds16(const void* g, void* l) {
    __builtin_amdgcn_global_load_lds(
        (const __attribute__((address_space(1))) unsigned int*)g,
        (__attribute__((address_space(3))) unsigned int*)l, 16, 0, 0);
}

// ---- pre-convert: z -> zh (XOR-permuted) + zl (linear) ----
__global__ __launch_bounds__(256) void zconv_kernel(const float* __restrict__ z,
                                                    unsigned short* __restrict__ zh,
                                                    unsigned short* __restrict__ zl) {
    int q = blockIdx.x * 256 + threadIdx.x;       // float4 index, 0..1048575
    float4 v = reinterpret_cast<const float4*>(z)[q];
    us4 h, lo;
    h[0] = f2bf(v.x); lo[0] = f2bf(v.x - bf2f(h[0]));
    h[1] = f2bf(v.y); lo[1] = f2bf(v.y - bf2f(h[1]));
    h[2] = f2bf(v.z); lo[2] = f2bf(v.z - bf2f(h[2]));
    h[3] = f2bf(v.w); lo[3] = f2bf(v.w - bf2f(h[3]));
    int row = q >> 6;                              // 64 float4 per 256-elem row
    int ob  = (q & 63) * 8;                        // byte offset in 512B bf16 row
    int sb  = (ob & ~127) | ((ob & 127) ^ ((row & 7) << 4));
    *reinterpret_cast<us4*>((char*)zh + (size_t)row * 512 + sb) = h;
    reinterpret_cast<us4*>(zl)[q] = lo;            // linear
}

// ---- pre-convert: emb -> eh/el (linear) + enorm ----
__global__ __launch_bounds__(256) void econv_kernel(const float* __restrict__ emb,
                                                    unsigned short* __restrict__ eh,
                                                    unsigned short* __restrict__ el,
                                                    float* __restrict__ enorm) {
    int row  = blockIdx.x * 4 + (threadIdx.x >> 6);
    int lane = threadIdx.x & 63;
    float4 v = reinterpret_cast<const float4*>(emb + (size_t)row * D_DIM)[lane];

    float s = v.x * v.x + v.y * v.y + v.z * v.z + v.w * v.w;
    #pragma unroll
    for (int off = 32; off >= 1; off >>= 1) s += __shfl_down(s, off);
    if (lane == 0) enorm[row] = s;

    us4 h, lo;
    h[0] = f2bf(v.x); lo[0] = f2bf(v.x - bf2f(h[0]));
    h[1] = f2bf(v.y); lo[1] = f2bf(v.y - bf2f(h[1]));
    h[2] = f2bf(v.z); lo[2] = f2bf(v.z - bf2f(h[2]));
    h[3] = f2bf(v.w); lo[3] = f2bf(v.w - bf2f(h[3]));
    size_t o = (size_t)row * 512 + lane * 8;
    *reinterpret_cast<us4*>((char*)eh + o) = h;
    *reinterpret_cast<us4*>((char*)el + o) = lo;
}

// ---------------- MFMA argmin: barrier-free K-loop ----------------
// A-hi: LDS, staged ONCE per block (gl2lds from permuted zh, XOR-read).
// A-lo: registers for the whole block (static-indexed al_reg).
// B (eh/el): direct per-lane global loads from linear planes (L1/L2-shared).
__global__ __launch_bounds__(256, 2) void argmin_kernel(const unsigned short* __restrict__ zh,
                                                        const unsigned short* __restrict__ zl,
                                                        const unsigned short* __restrict__ eh,
                                                        const unsigned short* __restrict__ el,
                                                        const float* __restrict__ enorm,
                                                        u64* __restrict__ cand) {
    __shared__ __align__(16) unsigned short ash[BM * D_DIM];   // 64KB, A-hi full-D

    const int tid = threadIdx.x;
    const int wv  = tid >> 6;          // wave 0..3 -> rows wv*32..+31
    const int l   = tid & 63;
    const int lr  = l & 15;            // A: row-in-frag / B: code-in-frag / D: col
    const int lg  = l >> 4;            // k-group; D: row-quad
    const int lg16 = lg * 16;
    const int r0    = blockIdx.x * BM;
    const int cbase = blockIdx.y * KCHUNK;

    const char* ehp = (const char*)eh;
    const char* elp = (const char*)el;

    // ---- stage A-hi into LDS (linear copy of pre-permuted plane) ----
    #pragma unroll
    for (int it = 0; it < 16; ++it) {
        int q = it * 256 + tid;                     // 16B-chunk index, 0..4095
        gl2lds16((const char*)zh + (size_t)r0 * 512 + (size_t)q * 16,
                 (char*)ash + (it * 256 + wv * 64) * 16);
    }
    // ---- A-lo fragments into registers (whole block's worth) ----
    s8v al_reg[4][2][2];                            // [d0b][kf][i] — static-indexed only
    {
        const char* zlp = (const char*)zl;
        #pragma unroll
        for (int d = 0; d < 4; ++d)
            #pragma unroll
            for (int kf = 0; kf < 2; ++kf)
                #pragma unroll
                for (int i = 0; i < 2; ++i) {
                    size_t o = (size_t)(r0 + wv * 32 + i * 16 + lr) * 512
                             + d * 128 + kf * 64 + lg16;
                    al_reg[d][kf][i] = *reinterpret_cast<const s8v*>(zlp + o);
                }
    }
    __syncthreads();                                // A-hi staged; only barrier

    // A-hi LDS read bases
    int abase[2], aswz[2];
    #pragma unroll
    for (int i = 0; i < 2; ++i) {
        int row = wv * 32 + i * 16 + lr;
        abase[i] = row * 512; aswz[i] = (row & 7) << 4;
    }

    u64 t1[8], t2[8];
    #pragma unroll
    for (int q = 0; q < 8; ++q) { t1[q] = ~0ULL; t2[q] = ~0ULL; }

    for (int ct = 0; ct < KCHUNK; ct += BN) {
        f4v acc[2][8];
        #pragma unroll
        for (int i = 0; i < 2; ++i)
            #pragma unroll
            for (int j = 0; j < 8; ++j)
                acc[i][j] = (f4v){0.f, 0.f, 0.f, 0.f};

        #pragma unroll
        for (int d0b = 0; d0b < 4; ++d0b) {
            #pragma unroll
            for (int kf = 0; kf < 2; ++kf) {
                const int kb = d0b * 128 + kf * 64 + lg16;
                s8v ah[2];
                #pragma unroll
                for (int i = 0; i < 2; ++i)
                    ah[i] = *reinterpret_cast<const s8v*>(
                        (const char*)ash + abase[i] + (kb ^ aswz[i]));
                #pragma unroll
                for (int jh = 0; jh < 2; ++jh) {
                    s8v bh[4], bl[4];
                    #pragma unroll
                    for (int jj = 0; jj < 4; ++jj) {
                        size_t o = (size_t)(cbase + ct + (jh * 4 + jj) * 16 + lr) * 512
                                 + (size_t)kb;
                        bh[jj] = *reinterpret_cast<const s8v*>(ehp + o);
                        bl[jj] = *reinterpret_cast<const s8v*>(elp + o);
                    }
                    #pragma unroll
                    for (int i = 0; i < 2; ++i)
                        #pragma unroll
                        for (int jj = 0; jj < 4; ++jj) {
                            int j = jh * 4 + jj;
                            acc[i][j] = __builtin_amdgcn_mfma_f32_16x16x32_bf16(
                                ah[i], bh[jj], acc[i][j], 0, 0, 0);
                            acc[i][j] = __builtin_amdgcn_mfma_f32_16x16x32_bf16(
                                ah[i], bl[jj], acc[i][j], 0, 0, 0);
                            acc[i][j] = __builtin_amdgcn_mfma_f32_16x16x32_bf16(
                                al_reg[d0b][kf][i], bh[jj], acc[i][j], 0, 0, 0);
                        }
                }
            }
        }

        // epilogue: dist = enorm[c] - 2*dot ; reduce over j, update per-row top-2
        float en[8];
        #pragma unroll
        for (int j = 0; j < 8; ++j) en[j] = enorm[cbase + ct + j * 16 + lr];

        #pragma unroll
        for (int i = 0; i < 2; ++i)
            #pragma unroll
            for (int r = 0; r < 4; ++r) {
                float m = fmaf(-2.f, acc[i][0][r], en[0]);
                int  mj = 0;
                #pragma unroll
                for (int j = 1; j < 8; ++j) {
                    float dj = fmaf(-2.f, acc[i][j][r], en[j]);
                    if (dj < m) { m = dj; mj = j; }
                }
                u32 c = (u32)(cbase + ct + mj * 16 + lr);
                u64 key = ((u64)f2ord(m) << 32) | c;
                int q = i * 4 + r;
                if (key < t1[q])      { t2[q] = t1[q]; t1[q] = key; }
                else if (key < t2[q]) { t2[q] = key; }
            }
    }

    // cross-lane top-2 merge within each 16-lane group, then write cand
    #pragma unroll
    for (int i = 0; i < 2; ++i)
        #pragma unroll
        for (int r = 0; r < 4; ++r) {
            int q = i * 4 + r;
            u64 a1 = t1[q], a2 = t2[q];
            #pragma unroll
            for (int mk = 1; mk <= 8; mk <<= 1) {
                u64 o1 = __shfl_xor(a1, mk);
                u64 o2 = __shfl_xor(a2, mk);
                u64 n1 = a1 < o1 ? a1 : o1;
                u64 hi = a1 < o1 ? o1 : a1;
                u64 m2 = a2 < o2 ? a2 : o2;
                a1 = n1;
                a2 = hi < m2 ? hi : m2;
            }
            if (lr == 0) {
                int row_g = r0 + wv * 32 + i * 16 + lg * 4 + r;
                u64* dst = &cand[((size_t)row_g * NCHUNK + blockIdx.y) * 2];
                dst[0] = a1; dst[1] = a2;
            }
        }
}

// ---------------- fallback (round-5 proven path, used if ws too small) ----------------
__global__ __launch_bounds__(256) void enorm_kernel(const float* __restrict__ emb,
                                                    float* __restrict__ enorm) {
    int row  = blockIdx.x * 4 + (threadIdx.x >> 6);
    int lane = threadIdx.x & 63;
    float4 v = reinterpret_cast<const float4*>(emb + (size_t)row * D_DIM)[lane];
    float s = v.x * v.x + v.y * v.y + v.z * v.z + v.w * v.w;
    #pragma unroll
    for (int off = 32; off >= 1; off >>= 1) s += __shfl_down(s, off);
    if (lane == 0) enorm[row] = s;
}

__global__ __launch_bounds__(256, 2) void argmin_fb_kernel(const float* __restrict__ z,
                                                           const float* __restrict__ emb,
                                                           const float* __restrict__ enorm,
                                                           u64* __restrict__ cand) {
    __shared__ __align__(16) unsigned short zsh[BM * 64];
    __shared__ __align__(16) unsigned short zsl[BM * 64];
    __shared__ __align__(16) unsigned short esh[BN * 64];
    __shared__ __align__(16) unsigned short esl[BN * 64];

    const int tid = threadIdx.x;
    const int wv  = tid >> 6;
    const int l   = tid & 63;
    const int lr  = l & 15;
    const int lg  = l >> 4;
    const int r0    = blockIdx.x * BM;
    const int cbase = blockIdx.y * KCHUNK;

    u64 t1[8], t2[8];
    #pragma unroll
    for (int q = 0; q < 8; ++q) { t1[q] = ~0ULL; t2[q] = ~0ULL; }

    int arb[2], asw[2], brb[8], bsw[8];
    #pragma unroll
    for (int i = 0; i < 2; ++i) {
        int row = wv * 32 + i * 16 + lr;
        arb[i] = row * 128; asw[i] = (row & 7) << 4;
    }
    #pragma unroll
    for (int j = 0; j < 8; ++j) {
        int row = j * 16 + lr;
        brb[j] = row * 128; bsw[j] = (row & 7) << 4;
    }

    for (int ct = 0; ct < KCHUNK; ct += BN) {
        f4v acc[2][8];
        #pragma unroll
        for (int i = 0; i < 2; ++i)
            #pragma unroll
            for (int j = 0; j < 8; ++j)
                acc[i][j] = (f4v){0.f, 0.f, 0.f, 0.f};

        for (int d0 = 0; d0 < D_DIM; d0 += 64) {
            __syncthreads();
            #pragma unroll
            for (int it = 0; it < 8; ++it) {
                int q   = tid + it * 256;
                int row = q >> 4;
                int f4  = q & 15;
                int wo  = row * 128 + ((f4 * 8) ^ ((row & 7) << 4));

                float4 vz = *reinterpret_cast<const float4*>(
                    &z[(size_t)(r0 + row) * D_DIM + d0 + f4 * 4]);
                us4 h, lo;
                h[0] = f2bf(vz.x); lo[0] = f2bf(vz.x - bf2f(h[0]));
                h[1] = f2bf(vz.y); lo[1] = f2bf(vz.y - bf2f(h[1]));
                h[2] = f2bf(vz.z); lo[2] = f2bf(vz.z - bf2f(h[2]));
                h[3] = f2bf(vz.w); lo[3] = f2bf(vz.w - bf2f(h[3]));
                *reinterpret_cast<us4*>(reinterpret_cast<char*>(zsh) + wo) = h;
                *reinterpret_cast<us4*>(reinterpret_cast<char*>(zsl) + wo) = lo;

                float4 ve = *reinterpret_cast<const float4*>(
                    &emb[(size_t)(cbase + ct + row) * D_DIM + d0 + f4 * 4]);
                h[0] = f2bf(ve.x); lo[0] = f2bf(ve.x - bf2f(h[0]));
                h[1] = f2bf(ve.y); lo[1] = f2bf(ve.y - bf2f(h[1]));
                h[2] = f2bf(ve.z); lo[2] = f2bf(ve.z - bf2f(h[2]));
                h[3] = f2bf(ve.w); lo[3] = f2bf(ve.w - bf2f(h[3]));
                *reinterpret_cast<us4*>(reinterpret_cast<char*>(esh) + wo) = h;
                *reinterpret_cast<us4*>(reinterpret_cast<char*>(esl) + wo) = lo;
            }
            __syncthreads();

            #pragma unroll
            for (int kf = 0; kf < 2; ++kf) {
                const int kb = kf * 64 + lg * 16;
                s8v ah[2], al[2];
                #pragma unroll
                for (int i = 0; i < 2; ++i) {
                    int o = arb[i] + (kb ^ asw[i]);
                    ah[i] = *reinterpret_cast<const s8v*>(reinterpret_cast<const char*>(zsh) + o);
                    al[i] = *reinterpret_cast<const s8v*>(reinterpret_cast<const char*>(zsl) + o);
                }
                #pragma unroll
                for (int jh = 0; jh < 2; ++jh) {
                    s8v bh[4], bl[4];
                    #pragma unroll
                    for (int jj = 0; jj < 4; ++jj) {
                        int j = jh * 4 + jj;
                        int o = brb[j] + (kb ^ bsw[j]);
                        bh[jj] = *reinterpret_cast<const s8v*>(reinterpret_cast<const char*>(esh) + o);
                        bl[jj] = *reinterpret_cast<const s8v*>(reinterpret_cast<const char*>(esl) + o);
                    }
                    #pragma unroll
                    for (int i = 0; i < 2; ++i)
                        #pragma unroll
                        for (int jj = 0; jj < 4; ++jj) {
                            int j = jh * 4 + jj;
                            acc[i][j] = __builtin_amdgcn_mfma_f32_16x16x32_bf16(ah[i], bh[jj], acc[i][j], 0, 0, 0);
                            acc[i][j] = __builtin_amdgcn_mfma_f32_16x16x32_bf16(ah[i], bl[jj], acc[i][j], 0, 0, 0);
                            acc[i][j] = __builtin_amdgcn_mfma_f32_16x16x32_bf16(al[i], bh[jj], acc[i][j], 0, 0, 0);
                        }
                }
            }
        }

        float en[8];
        #pragma unroll
        for (int j = 0; j < 8; ++j) en[j] = enorm[cbase + ct + j * 16 + lr];

        #pragma unroll
        for (int i = 0; i < 2; ++i)
            #pragma unroll
            for (int r = 0; r < 4; ++r) {
                float m = fmaf(-2.f, acc[i][0][r], en[0]);
                int  mj = 0;
                #pragma unroll
                for (int j = 1; j < 8; ++j) {
                    float dj = fmaf(-2.f, acc[i][j][r], en[j]);
                    if (dj < m) { m = dj; mj = j; }
                }
                u32 c = (u32)(cbase + ct + mj * 16 + lr);
                u64 key = ((u64)f2ord(m) << 32) | c;
                int q = i * 4 + r;
                if (key < t1[q])      { t2[q] = t1[q]; t1[q] = key; }
                else if (key < t2[q]) { t2[q] = key; }
            }
    }

    #pragma unroll
    for (int i = 0; i < 2; ++i)
        #pragma unroll
        for (int r = 0; r < 4; ++r) {
            int q = i * 4 + r;
            u64 a1 = t1[q], a2 = t2[q];
            #pragma unroll
            for (int mk = 1; mk <= 8; mk <<= 1) {
                u64 o1 = __shfl_xor(a1, mk);
                u64 o2 = __shfl_xor(a2, mk);
                u64 n1 = a1 < o1 ? a1 : o1;
                u64 hi = a1 < o1 ? o1 : a1;
                u64 m2 = a2 < o2 ? a2 : o2;
                a1 = n1;
                a2 = hi < m2 ? hi : m2;
            }
            if (lr == 0) {
                int row_g = r0 + wv * 32 + i * 16 + lg * 4 + r;
                u64* dst = &cand[((size_t)row_g * NCHUNK + blockIdx.y) * 2];
                dst[0] = a1; dst[1] = a2;
            }
        }
}

// ---------------- exact fp32 rescore of 16 candidates + outputs ----------------
__global__ __launch_bounds__(256) void rescore_kernel(const float* __restrict__ z,
                                                      const float* __restrict__ emb,
                                                      const float* __restrict__ enorm,
                                                      const u64* __restrict__ cand,
                                                      float* __restrict__ out,
                                                      float* __restrict__ partials) {
    int row  = blockIdx.x * 4 + (threadIdx.x >> 6);
    int lane = threadIdx.x & 63;
    float4 zv = reinterpret_cast<const float4*>(z)[(size_t)row * 64 + lane];

    u64 best = ~0ULL;
    for (int s = 0; s < 2 * NCHUNK; ++s) {
        u32 c = ((u32)cand[(size_t)row * (2 * NCHUNK) + s]) & (K_CODES - 1);
        float4 ev = reinterpret_cast<const float4*>(emb)[(size_t)c * 64 + lane];
        float p = zv.x * ev.x + zv.y * ev.y + zv.z * ev.z + zv.w * ev.w;
        #pragma unroll
        for (int mk = 1; mk < 64; mk <<= 1) p += __shfl_xor(p, mk);
        float dist = fmaf(-2.f, p, enorm[c]);
        u64 key = ((u64)f2ord(dist) << 32) | c;
        best = key < best ? key : best;
    }
    u32 idx = ((u32)best) & (K_CODES - 1);
    if (lane == 0) out[IDX_OFF + row] = (float)idx;

    float4 ev = reinterpret_cast<const float4*>(emb)[(size_t)idx * 64 + lane];
    float tx = ev.x - zv.x, ty = ev.y - zv.y, tz = ev.z - zv.z, tw = ev.w - zv.w;
    float4 o;
    o.x = zv.x + tx; o.y = zv.y + ty; o.z = zv.z + tz; o.w = zv.w + tw;  // straight-through
    reinterpret_cast<float4*>(out)[(size_t)row * 64 + lane] = o;

    float s = tx * tx + ty * ty + tz * tz + tw * tw;
    #pragma unroll
    for (int off = 32; off >= 1; off >>= 1) s += __shfl_down(s, off);

    __shared__ float wsum[4];
    if (lane == 0) wsum[threadIdx.x >> 6] = s;
    __syncthreads();
    if (threadIdx.x == 0)
        partials[blockIdx.x] = (wsum[0] + wsum[1]) + (wsum[2] + wsum[3]);
}

__global__ __launch_bounds__(256) void loss_kernel(const float* __restrict__ partials,
                                                   float* __restrict__ out) {
    __shared__ float sm[256];
    float s = 0.0f;
    for (int i = threadIdx.x; i < 4096; i += 256) s += partials[i];
    sm[threadIdx.x] = s;
    __syncthreads();
    #pragma unroll
    for (int st = 128; st >= 1; st >>= 1) {
        if (threadIdx.x < st) sm[threadIdx.x] += sm[threadIdx.x + st];
        __syncthreads();
    }
    if (threadIdx.x == 0)
        out[LOSS_OFF] = sm[0] * (0.25f / (float)(N_ROWS * D_DIM));
}

extern "C" void kernel_launch(void* const* d_in, const int* in_sizes, int n_in,
                              void* d_out, int out_size, void* d_ws, size_t ws_size,
                              hipStream_t stream) {
    const float* z   = (const float*)d_in[0];
    const float* emb = (const float*)d_in[1];
    float* out = (float*)d_out;

    u64*   cand     = (u64*)d_ws;
    float* enorm    = (float*)((char*)d_ws + WS_ENORM_OFF);
    float* partials = (float*)((char*)d_ws + WS_PARTIAL_OFF);

    if (ws_size >= WS_NEED) {
        unsigned short* zh = (unsigned short*)((char*)d_ws + WS_ZH_OFF);
        unsigned short* zl = (unsigned short*)((char*)d_ws + WS_ZL_OFF);
        unsigned short* eh = (unsigned short*)((char*)d_ws + WS_EH_OFF);
        unsigned short* el = (unsigned short*)((char*)d_ws + WS_EL_OFF);
        zconv_kernel<<<(N_ROWS * D_DIM / 4) / 256, 256, 0, stream>>>(z, zh, zl);
        econv_kernel<<<K_CODES / 4, 256, 0, stream>>>(emb, eh, el, enorm);
        argmin_kernel<<<dim3(N_ROWS / BM, NCHUNK), 256, 0, stream>>>(zh, zl, eh, el, enorm, cand);
    } else {
        enorm_kernel<<<K_CODES / 4, 256, 0, stream>>>(emb, enorm);
        argmin_fb_kernel<<<dim3(N_ROWS / BM, NCHUNK), 256, 0, stream>>>(z, emb, enorm, cand);
    }
    rescore_kernel<<<N_ROWS / 4, 256, 0, stream>>>(z, emb, enorm, cand, out, partials);
    loss_kernel<<<1, 256, 0, stream>>>(partials, out);
}

// Round 9
// 353.895 us; speedup vs baseline: 1.6215x; 1.6215x over previous
//
#include <hip/hip_runtime.h>
#include <math.h>

#define D_DIM   256
#define N_ROWS  16384
#define K_CODES 8192
#define NCHUNK  8          // 8 chunks of 1024 codes; chunk -> XCD

typedef __attribute__((ext_vector_type(8))) short s8v;           // 8 bf16 (A/B frag)
typedef __attribute__((ext_vector_type(4))) float f4v;           // 4 f32  (C/D frag)
typedef __attribute__((ext_vector_type(4))) unsigned short us4;  // 4 bf16 (8B write)
typedef unsigned long long u64;
typedef unsigned int u32;

// out layout: [0, 4194304) z_q_st | [4194304, 4210688) indices (as float) | [4210688] vq_loss
#define IDX_OFF  ((size_t)N_ROWS * D_DIM)
#define LOSS_OFF (IDX_OFF + N_ROWS)

// ws layout (26.05 MB used; harness ws >= 28MB confirmed rounds 6-8):
//   [0, 2MB)        u64 cand[N_ROWS][NCHUNK][2]
//   [2MB, +32KB)    float enorm[8192]
//   [+32KB, +16KB)  float partials[4096]
//   [3MB, 11MB)     bf16 zh_t[8][16384][32]   (K-tiled: [d0-tile][row][64B])
//   [11MB, 19MB)    bf16 zl_t[8][16384][32]
//   [19MB, 23MB)    bf16 eh_t[8][8192][32]
//   [23MB, 27MB)    bf16 el_t[8][8192][32]
#define WS_ENORM_OFF    (2u * 1024u * 1024u)
#define WS_PARTIAL_OFF  (WS_ENORM_OFF + 32768u)
#define WS_ZH_OFF       (3u * 1024u * 1024u)
#define WS_ZL_OFF       (11u * 1024u * 1024u)
#define WS_EH_OFF       (19u * 1024u * 1024u)
#define WS_EL_OFF       (23u * 1024u * 1024u)

__device__ __forceinline__ unsigned short f2bf(float f) {   // fp32 -> bf16 RNE
    u32 u = __float_as_uint(f);
    return (unsigned short)((u + 0x7fffu + ((u >> 16) & 1u)) >> 16);
}
__device__ __forceinline__ float bf2f(unsigned short b) {
    return __uint_as_float(((u32)b) << 16);
}
__device__ __forceinline__ u32 f2ord(float f) {             // monotonic fp32 -> u32
    u32 u = __float_as_uint(f);
    return (u & 0x80000000u) ? ~u : (u | 0x80000000u);
}
__device__ __forceinline__ void gl2lds16(const void* g, void* l) {
    __builtin_amdgcn_global_load_lds(
        (const __attribute__((address_space(1))) unsigned int*)g,
        (__attribute__((address_space(3))) unsigned int*)l, 16, 0, 0);
}

// ---- pre-convert: z -> zh_t, zl_t (K-tiled) ----
__global__ __launch_bounds__(256) void zconv_kernel(const float* __restrict__ z,
                                                    unsigned short* __restrict__ zh,
                                                    unsigned short* __restrict__ zl) {
    int q = blockIdx.x * 256 + threadIdx.x;        // float4 index, 0..1048575
    float4 v = reinterpret_cast<const float4*>(z)[q];
    us4 h, lo;
    h[0] = f2bf(v.x); lo[0] = f2bf(v.x - bf2f(h[0]));
    h[1] = f2bf(v.y); lo[1] = f2bf(v.y - bf2f(h[1]));
    h[2] = f2bf(v.z); lo[2] = f2bf(v.z - bf2f(h[2]));
    h[3] = f2bf(v.w); lo[3] = f2bf(v.w - bf2f(h[3]));
    int row = q >> 6;                               // 64 float4 per row
    int f   = q & 63;
    int d0b = f >> 3, k8 = f & 7;
    size_t off = (size_t)(d0b * N_ROWS + row) * 64 + k8 * 8;
    *reinterpret_cast<us4*>((char*)zh + off) = h;
    *reinterpret_cast<us4*>((char*)zl + off) = lo;
}

// ---- pre-convert: emb -> eh_t, el_t (K-tiled) ----
__global__ __launch_bounds__(256) void econv_kernel(const float* __restrict__ emb,
                                                    unsigned short* __restrict__ eh,
                                                    unsigned short* __restrict__ el) {
    int q = blockIdx.x * 256 + threadIdx.x;        // 0..524287
    float4 v = reinterpret_cast<const float4*>(emb)[q];
    us4 h, lo;
    h[0] = f2bf(v.x); lo[0] = f2bf(v.x - bf2f(h[0]));
    h[1] = f2bf(v.y); lo[1] = f2bf(v.y - bf2f(h[1]));
    h[2] = f2bf(v.z); lo[2] = f2bf(v.z - bf2f(h[2]));
    h[3] = f2bf(v.w); lo[3] = f2bf(v.w - bf2f(h[3]));
    int row = q >> 6;
    int f   = q & 63;
    int d0b = f >> 3, k8 = f & 7;
    size_t off = (size_t)(d0b * K_CODES + row) * 64 + k8 * 8;
    *reinterpret_cast<us4*>((char*)eh + off) = h;
    *reinterpret_cast<us4*>((char*)el + off) = lo;
}

__global__ __launch_bounds__(256) void enorm_kernel(const float* __restrict__ emb,
                                                    float* __restrict__ enorm) {
    int row  = blockIdx.x * 4 + (threadIdx.x >> 6);
    int lane = threadIdx.x & 63;
    float4 v = reinterpret_cast<const float4*>(emb + (size_t)row * D_DIM)[lane];
    float s = v.x * v.x + v.y * v.y + v.z * v.z + v.w * v.w;
    #pragma unroll
    for (int off = 32; off >= 1; off >>= 1) s += __shfl_down(s, off);
    if (lane == 0) enorm[row] = s;
}

// ---------------- MFMA argmin: swapped operands (A=codes, B=rows) ----------------
// Block: 256 codes x 128 rows; 4 waves (wm,wn) each 128 codes x 64 rows.
// LDS 48KB: eh 16KB | el 16KB | zh 8KB | zl 8KB, staged per (ct, d0b) via gl2lds
// from K-tiled planes (contiguous src, linear dst, conflict-free 1KB frag reads).
__global__ __launch_bounds__(256) void argmin_kernel(const unsigned short* __restrict__ zh,
                                                     const unsigned short* __restrict__ zl,
                                                     const unsigned short* __restrict__ eh,
                                                     const unsigned short* __restrict__ el,
                                                     const float* __restrict__ enorm,
                                                     u64* __restrict__ cand) {
    __shared__ __align__(16) unsigned char lds[49152];

    const int tid = threadIdx.x;
    const int wv  = tid >> 6;
    const int l   = tid & 63;
    const int lr  = l & 15;
    const int lg  = l >> 4;
    const int wm  = wv >> 1;                // row-half: rows wm*64..+63
    const int wn  = wv & 1;                 // code-half: codes wn*128..+127
    const int wg  = blockIdx.x;
    const int r0    = (wg >> 3) * 128;
    const int ch    = wg & 7;               // chunk == XCD (round-robin dispatch)
    const int cbase = ch * 1024;

    const char* zhp = (const char*)zh;
    const char* zlp = (const char*)zl;
    const char* ehp = (const char*)eh;
    const char* elp = (const char*)el;

    u64 t1[4], t2[4];                       // top-2 per owned row-tile j
    #pragma unroll
    for (int j = 0; j < 4; ++j) { t1[j] = ~0ULL; t2[j] = ~0ULL; }

    for (int ct = 0; ct < 4; ++ct) {
        const int cb = cbase + ct * 256;
        f4v acc[8][4];
        #pragma unroll
        for (int i = 0; i < 8; ++i)
            #pragma unroll
            for (int j = 0; j < 4; ++j)
                acc[i][j] = (f4v){0.f, 0.f, 0.f, 0.f};

        for (int d0b = 0; d0b < 8; ++d0b) {
            const size_t ebase = (size_t)(d0b * K_CODES + cb) * 64;
            const size_t zbase = (size_t)(d0b * N_ROWS + r0) * 64;
            __syncthreads();                               // prev readers done
            #pragma unroll
            for (int it = 0; it < 4; ++it) {               // eh: 16KB
                int u = it * 256 + tid;
                gl2lds16(ehp + ebase + (size_t)u * 16, (char*)lds + u * 16);
            }
            #pragma unroll
            for (int it = 0; it < 4; ++it) {               // el: 16KB
                int u = it * 256 + tid;
                gl2lds16(elp + ebase + (size_t)u * 16, (char*)lds + 16384 + u * 16);
            }
            #pragma unroll
            for (int it = 0; it < 2; ++it) {               // zh: 8KB
                int u = it * 256 + tid;
                gl2lds16(zhp + zbase + (size_t)u * 16, (char*)lds + 32768 + u * 16);
            }
            #pragma unroll
            for (int it = 0; it < 2; ++it) {               // zl: 8KB
                int u = it * 256 + tid;
                gl2lds16(zlp + zbase + (size_t)u * 16, (char*)lds + 40960 + u * 16);
            }
            __syncthreads();                               // tiles ready

            s8v zhf[4], zlf[4];
            #pragma unroll
            for (int j = 0; j < 4; ++j) {
                int row = wm * 64 + j * 16 + lr;
                zhf[j] = *reinterpret_cast<const s8v*>(lds + 32768 + row * 64 + lg * 16);
                zlf[j] = *reinterpret_cast<const s8v*>(lds + 40960 + row * 64 + lg * 16);
            }
            #pragma unroll
            for (int i = 0; i < 8; ++i) {
                int code = wn * 128 + i * 16 + lr;
                s8v ehf = *reinterpret_cast<const s8v*>(lds + code * 64 + lg * 16);
                s8v elf = *reinterpret_cast<const s8v*>(lds + 16384 + code * 64 + lg * 16);
                #pragma unroll
                for (int j = 0; j < 4; ++j) {
                    acc[i][j] = __builtin_amdgcn_mfma_f32_16x16x32_bf16(ehf, zhf[j], acc[i][j], 0, 0, 0);
                    acc[i][j] = __builtin_amdgcn_mfma_f32_16x16x32_bf16(elf, zhf[j], acc[i][j], 0, 0, 0);
                    acc[i][j] = __builtin_amdgcn_mfma_f32_16x16x32_bf16(ehf, zlf[j], acc[i][j], 0, 0, 0);
                }
            }
        }

        // epilogue: dist = enorm[c] - 2*dot; D row-quad = code, D col = z-row
        #pragma unroll
        for (int i = 0; i < 8; ++i)
            #pragma unroll
            for (int r = 0; r < 4; ++r) {
                int code = cb + wn * 128 + i * 16 + lg * 4 + r;
                float en = enorm[code];
                #pragma unroll
                for (int j = 0; j < 4; ++j) {
                    float dist = fmaf(-2.f, acc[i][j][r], en);
                    u64 key = ((u64)f2ord(dist) << 32) | (u32)code;
                    if (key < t1[j])      { t2[j] = t1[j]; t1[j] = key; }
                    else if (key < t2[j]) { t2[j] = key; }
                }
            }
    }

    // cross-lane (lg) top-2 merge: lanes sharing (j, lr) hold same row
    #pragma unroll
    for (int j = 0; j < 4; ++j) {
        u64 a1 = t1[j], a2 = t2[j];
        #pragma unroll
        for (int mk = 16; mk <= 32; mk <<= 1) {
            u64 o1 = __shfl_xor(a1, mk);
            u64 o2 = __shfl_xor(a2, mk);
            u64 n1 = a1 < o1 ? a1 : o1;
            u64 hi = a1 < o1 ? o1 : a1;
            u64 m2 = a2 < o2 ? a2 : o2;
            a1 = n1;
            a2 = hi < m2 ? hi : m2;
        }
        t1[j] = a1; t2[j] = a2;
    }

    // cross-wave (wn) merge via LDS, then write cand[row][ch][2]
    __syncthreads();
    u64* mbuf = (u64*)lds;                   // 2KB reuse
    if (wn == 1 && lg == 0) {
        #pragma unroll
        for (int j = 0; j < 4; ++j) {
            int s = ((wm * 4 + j) * 16 + lr) * 2;
            mbuf[s] = t1[j]; mbuf[s + 1] = t2[j];
        }
    }
    __syncthreads();
    if (wn == 0 && lg == 0) {
        #pragma unroll
        for (int j = 0; j < 4; ++j) {
            int s = ((wm * 4 + j) * 16 + lr) * 2;
            u64 b1 = mbuf[s], b2 = mbuf[s + 1];
            u64 n1 = t1[j] < b1 ? t1[j] : b1;
            u64 hi = t1[j] < b1 ? b1 : t1[j];
            u64 m2 = t2[j] < b2 ? t2[j] : b2;
            u64 n2 = hi < m2 ? hi : m2;
            int row = r0 + wm * 64 + j * 16 + lr;
            cand[((size_t)row * NCHUNK + ch) * 2]     = n1;
            cand[((size_t)row * NCHUNK + ch) * 2 + 1] = n2;
        }
    }
}

// ---------------- exact fp32 rescore of 16 candidates + outputs ----------------
__global__ __launch_bounds__(256) void rescore_kernel(const float* __restrict__ z,
                                                      const float* __restrict__ emb,
                                                      const float* __restrict__ enorm,
                                                      const u64* __restrict__ cand,
                                                      float* __restrict__ out,
                                                      float* __restrict__ partials) {
    int row  = blockIdx.x * 4 + (threadIdx.x >> 6);
    int lane = threadIdx.x & 63;
    float4 zv = reinterpret_cast<const float4*>(z)[(size_t)row * 64 + lane];

    u64 best = ~0ULL;
    for (int s = 0; s < 2 * NCHUNK; ++s) {
        u32 c = ((u32)cand[(size_t)row * (2 * NCHUNK) + s]) & (K_CODES - 1);
        float4 ev = reinterpret_cast<const float4*>(emb)[(size_t)c * 64 + lane];
        float p = zv.x * ev.x + zv.y * ev.y + zv.z * ev.z + zv.w * ev.w;
        #pragma unroll
        for (int mk = 1; mk < 64; mk <<= 1) p += __shfl_xor(p, mk);
        float dist = fmaf(-2.f, p, enorm[c]);
        u64 key = ((u64)f2ord(dist) << 32) | c;
        best = key < best ? key : best;
    }
    u32 idx = ((u32)best) & (K_CODES - 1);
    if (lane == 0) out[IDX_OFF + row] = (float)idx;

    float4 ev = reinterpret_cast<const float4*>(emb)[(size_t)idx * 64 + lane];
    float tx = ev.x - zv.x, ty = ev.y - zv.y, tz = ev.z - zv.z, tw = ev.w - zv.w;
    float4 o;
    o.x = zv.x + tx; o.y = zv.y + ty; o.z = zv.z + tz; o.w = zv.w + tw;  // straight-through
    reinterpret_cast<float4*>(out)[(size_t)row * 64 + lane] = o;

    float s = tx * tx + ty * ty + tz * tz + tw * tw;
    #pragma unroll
    for (int off = 32; off >= 1; off >>= 1) s += __shfl_down(s, off);

    __shared__ float wsum[4];
    if (lane == 0) wsum[threadIdx.x >> 6] = s;
    __syncthreads();
    if (threadIdx.x == 0)
        partials[blockIdx.x] = (wsum[0] + wsum[1]) + (wsum[2] + wsum[3]);
}

__global__ __launch_bounds__(256) void loss_kernel(const float* __restrict__ partials,
                                                   float* __restrict__ out) {
    __shared__ float sm[256];
    float s = 0.0f;
    for (int i = threadIdx.x; i < 4096; i += 256) s += partials[i];
    sm[threadIdx.x] = s;
    __syncthreads();
    #pragma unroll
    for (int st = 128; st >= 1; st >>= 1) {
        if (threadIdx.x < st) sm[threadIdx.x] += sm[threadIdx.x + st];
        __syncthreads();
    }
    if (threadIdx.x == 0)
        out[LOSS_OFF] = sm[0] * (0.25f / (float)(N_ROWS * D_DIM));
}

extern "C" void kernel_launch(void* const* d_in, const int* in_sizes, int n_in,
                              void* d_out, int out_size, void* d_ws, size_t ws_size,
                              hipStream_t stream) {
    const float* z   = (const float*)d_in[0];
    const float* emb = (const float*)d_in[1];
    float* out = (float*)d_out;

    u64*   cand     = (u64*)d_ws;
    float* enorm    = (float*)((char*)d_ws + WS_ENORM_OFF);
    float* partials = (float*)((char*)d_ws + WS_PARTIAL_OFF);
    unsigned short* zh = (unsigned short*)((char*)d_ws + WS_ZH_OFF);
    unsigned short* zl = (unsigned short*)((char*)d_ws + WS_ZL_OFF);
    unsigned short* eh = (unsigned short*)((char*)d_ws + WS_EH_OFF);
    unsigned short* el = (unsigned short*)((char*)d_ws + WS_EL_OFF);

    zconv_kernel<<<4096, 256, 0, stream>>>(z, zh, zl);
    econv_kernel<<<2048, 256, 0, stream>>>(emb, eh, el);
    enorm_kernel<<<K_CODES / 4, 256, 0, stream>>>(emb, enorm);
    argmin_kernel<<<1024, 256, 0, stream>>>(zh, zl, eh, el, enorm, cand);
    rescore_kernel<<<N_ROWS / 4, 256, 0, stream>>>(z, emb, enorm, cand, out, partials);
    loss_kernel<<<1, 256, 0, stream>>>(partials, out);
}